// Round 12
// baseline (293.455 us; speedup 1.0000x reference)
//
#include <hip/hip_runtime.h>
#include <math.h>

#define NVEC 32768   // 32*32*32 vectors
#define NE   1024    // codebook entries
#define ED   64      // embedding dim
#define TOT  2097152 // NVEC*ED total z elements
#define NCHUNK 8     // code chunks inside k_dist
#define CHUNK  128   // codes per chunk
#define MT     64    // vectors per k_dist block

// d_out offsets (in floats): loss | z_q_st | perplexity | min_encodings | idx
#define O_LOSS   0
#define O_ZQ     1
#define O_PERP   2097153
#define O_MINENC 2097154
#define O_IDX    35651586

// d_ws offsets (in floats). No ws memset: every cell read has a producer.
#define W_PIDX   0        // [32768] final idx (int), written by k_dist
#define W_CS     32768    // [1024]
#define W_SUMENC 33792    // [1024*64]
#define W_NEWEMB 99328    // [1024*64]
#define W_LOSSP  164864   // [2048]

// R11 post-mortem: SGEMM tile worked (k_dist < 85 µs) but the 8 chunk-blocks
// per vector-tile re-staged the same A-tile 8x, recomputed esq 512x, and
// round-tripped 9 MB pdist/pidx to feed a separate k_combine dispatch.
// Fused version: one block per 64-vector tile loops all 8 chunks in-kernel
// (A staged once, B per chunk), carries per-thread running argmin, merges
// with lexicographic (d,i) min — identical result to np.argmin first-index
// semantics — and writes final idx + one-hot rows directly. k_combine gone.
// Numerics bit-identical to R11 (passed): same ascending-c FMA chain per
// (n,k), zsq = 0.25*pairwise((2z)^2) (exact pow2 scaling), same esq.
__global__ void __launch_bounds__(256, 3) k_dist(const float* __restrict__ z,
                                                 const float* __restrict__ emb,
                                                 int* __restrict__ fidx,
                                                 float* __restrict__ out) {
    __shared__ __align__(16) float s_a[64 * 64];    // [c][m] : 2*z (16 KB)
    __shared__ __align__(16) float s_b[64 * 132];   // [c][k] : e chunk (33 KB)
    __shared__ float s_esq[CHUNK];
    __shared__ float s_zsq[MT];
    __shared__ int sbi[MT];

    int tid = threadIdx.x;
    int n0 = blockIdx.x * MT;
    int b = n0 >> 10, hw0 = n0 & 1023;  // MT=64 tile never crosses a b boundary
    const float* zb = z + b * 65536 + hw0;

    // Stage A once: 64c x 64m = 1024 float4, coalesced; store 2*z (exact x2)
#pragma unroll
    for (int j = 0; j < 4; ++j) {
        int f4i = j * 256 + tid;
        int c = f4i >> 4, pos = (f4i & 15) * 4;
        float4 v = *(const float4*)(zb + (c << 10) + pos);
        v.x = __fmul_rn(2.0f, v.x);
        v.y = __fmul_rn(2.0f, v.y);
        v.z = __fmul_rn(2.0f, v.z);
        v.w = __fmul_rn(2.0f, v.w);
        *(float4*)(s_a + c * 64 + pos) = v;
    }
    __syncthreads();

    // zsq once (threads 0..63): np-pairwise over z; from (2z): exact x0.25.
    if (tid < MT) {
        float r[8];
#pragma unroll
        for (int j = 0; j < 8; ++j) {
            float v = s_a[j * 64 + tid];
            r[j] = __fmul_rn(v, v);
        }
#pragma unroll
        for (int i = 8; i < 64; i += 8)
#pragma unroll
            for (int j = 0; j < 8; ++j) {
                float v = s_a[(i + j) * 64 + tid];
                r[j] = __fadd_rn(r[j], __fmul_rn(v, v));
            }
        s_zsq[tid] = __fmul_rn(0.25f, __fadd_rn(
            __fadd_rn(__fadd_rn(r[0], r[1]), __fadd_rn(r[2], r[3])),
            __fadd_rn(__fadd_rn(r[4], r[5]), __fadd_rn(r[6], r[7]))));
    }
    __syncthreads();

    int mi = tid & 15, ki = tid >> 4;
    int mbase = mi * 4, kbase = ki * 8;
    float zs[4];
#pragma unroll
    for (int mu = 0; mu < 4; ++mu) zs[mu] = s_zsq[mbase + mu];

    float bd[4];
    int bix[4];
#pragma unroll
    for (int mu = 0; mu < 4; ++mu) { bd[mu] = 3.4e38f; bix[mu] = kbase; }

    for (int q = 0; q < NCHUNK; ++q) {
        int k0 = q * CHUNK;
        __syncthreads();  // previous chunk's readers of s_b/s_esq are done
        // Stage B transposed: 128k x 64c, coalesced global f4 reads, scalar
        // LDS stores at stride 132 (16B-aligned quads for the compute reads)
#pragma unroll
        for (int j = 0; j < 8; ++j) {
            int f4i = j * 256 + tid;
            int kl = f4i >> 4, c0 = (f4i & 15) * 4;
            float4 v = *(const float4*)(emb + (size_t)(k0 + kl) * ED + c0);
            s_b[(c0 + 0) * 132 + kl] = v.x;
            s_b[(c0 + 1) * 132 + kl] = v.y;
            s_b[(c0 + 2) * 132 + kl] = v.z;
            s_b[(c0 + 3) * 132 + kl] = v.w;
        }
        // esq for this chunk from GLOBAL (independent of s_b staging -> no
        // extra barrier): np-pairwise, threads 0..127
        if (tid < CHUNK) {
            const float* ep = emb + (size_t)(k0 + tid) * ED;
            float r[8];
#pragma unroll
            for (int j = 0; j < 8; ++j) r[j] = __fmul_rn(ep[j], ep[j]);
#pragma unroll
            for (int i = 8; i < 64; i += 8)
#pragma unroll
                for (int j = 0; j < 8; ++j)
                    r[j] = __fadd_rn(r[j], __fmul_rn(ep[i + j], ep[i + j]));
            s_esq[tid] = __fadd_rn(
                __fadd_rn(__fadd_rn(r[0], r[1]), __fadd_rn(r[2], r[3])),
                __fadd_rn(__fadd_rn(r[4], r[5]), __fadd_rn(r[6], r[7])));
        }
        __syncthreads();

        float acc[4][8];
#pragma unroll
        for (int mu = 0; mu < 4; ++mu)
#pragma unroll
            for (int ku = 0; ku < 8; ++ku) acc[mu][ku] = 0.f;

#pragma unroll 4
        for (int c = 0; c < 64; ++c) {
            float4 av = *(const float4*)(s_a + c * 64 + mbase);
            float4 b0 = *(const float4*)(s_b + c * 132 + kbase);
            float4 b1 = *(const float4*)(s_b + c * 132 + kbase + 4);
#pragma unroll
            for (int mu = 0; mu < 4; ++mu) {
                float a = (&av.x)[mu];
                acc[mu][0] = __fmaf_rn(a, b0.x, acc[mu][0]);
                acc[mu][1] = __fmaf_rn(a, b0.y, acc[mu][1]);
                acc[mu][2] = __fmaf_rn(a, b0.z, acc[mu][2]);
                acc[mu][3] = __fmaf_rn(a, b0.w, acc[mu][3]);
                acc[mu][4] = __fmaf_rn(a, b1.x, acc[mu][4]);
                acc[mu][5] = __fmaf_rn(a, b1.y, acc[mu][5]);
                acc[mu][6] = __fmaf_rn(a, b1.z, acc[mu][6]);
                acc[mu][7] = __fmaf_rn(a, b1.w, acc[mu][7]);
            }
        }

        // d = fl(fl(zsq+esq) - dot2); running per-thread argmin. Thread's k
        // sequence (q asc, ku asc) is strictly increasing -> strict < keeps
        // the first index within this thread's candidate set.
#pragma unroll
        for (int mu = 0; mu < 4; ++mu)
#pragma unroll
            for (int ku = 0; ku < 8; ++ku) {
                float d = __fsub_rn(__fadd_rn(zs[mu], s_esq[kbase + ku]),
                                    acc[mu][ku]);
                if (d < bd[mu]) { bd[mu] = d; bix[mu] = k0 + kbase + ku; }
            }
    }

    // Merge the 16 ki candidates per m with lexicographic (d, i) min ==
    // np.argmin lowest-index-among-minima. Reuse s_b as scratch.
    __syncthreads();
    float* red_d = s_b;               // [16][64]
    int* red_i = (int*)(s_b + 1024);  // [16][64]
#pragma unroll
    for (int mu = 0; mu < 4; ++mu) {
        red_d[ki * 64 + mbase + mu] = bd[mu];
        red_i[ki * 64 + mbase + mu] = bix[mu];
    }
    __syncthreads();
    if (tid < MT) {
        float best = red_d[tid];
        int bi = red_i[tid];
#pragma unroll
        for (int q = 1; q < 16; ++q) {
            float d = red_d[q * 64 + tid];
            int i = red_i[q * 64 + tid];
            if (d < best || (d == best && i < bi)) { best = d; bi = i; }
        }
        fidx[n0 + tid] = bi;
        out[O_IDX + n0 + tid] = (float)bi;
        sbi[tid] = bi;
    }
    __syncthreads();
    // One-hot rows (replaces memset + k_combine): coalesced float2 stores.
    int wave = tid >> 6, lane = tid & 63;
    size_t base = (size_t)O_MINENC + (size_t)n0 * NE;
    for (int r = wave; r < MT; r += 4) {
        int rbi = sbi[r];
        float* rp = out + base + (size_t)r * NE;
#pragma unroll
        for (int s = 0; s < 8; ++s) {
            int col = s * 128 + lane * 2;
            float2 v;
            v.x = (col == rbi) ? 1.0f : 0.0f;
            v.y = (col + 1 == rbi) ? 1.0f : 0.0f;
            *(float2*)(rp + col) = v;
        }
    }
}

// Gather-based segment sum: one block per code k, 4 waves. Ballot-scan idx;
// members accumulated lane=element; popcount -> cs. Deterministic. No atomics.
__global__ void __launch_bounds__(256) k_sumenc(const int* __restrict__ idx,
                                                const float* __restrict__ z,
                                                float* __restrict__ cs,
                                                float* __restrict__ sumenc) {
    int k = blockIdx.x;
    int wave = threadIdx.x >> 6, lane = threadIdx.x & 63;
    float acc = 0.f;
    int cnt = 0;
    int base = wave * 8192;
    for (int it = 0; it < 128; ++it) {
        int n0 = base + it * 64;
        int idv = idx[n0 + lane];
        unsigned long long m = __ballot(idv == k);
        cnt += __popcll(m);
        while (m) {
            int bit = __ffsll((unsigned long long)m) - 1;  // ascending n
            m &= m - 1;
            int n = n0 + bit;
            int b = n >> 10, hw = n & 1023;
            acc = __fadd_rn(acc, z[b * 65536 + lane * 1024 + hw]);  // element c = lane
        }
    }
    __shared__ float sacc[4][64];
    __shared__ int scnt[4];
    sacc[wave][lane] = acc;
    if (lane == 0) scnt[wave] = cnt;
    __syncthreads();
    if (wave == 0) {
        float t = __fadd_rn(__fadd_rn(sacc[0][lane], sacc[1][lane]),
                            __fadd_rn(sacc[2][lane], sacc[3][lane]));
        sumenc[k * ED + lane] = t;
        if (lane == 0) cs[k] = (float)(scnt[0] + scnt[1] + scnt[2] + scnt[3]);
    }
}

// Single block, 1024 threads: EMA cluster-size + ntot/entropy reductions +
// perplexity + codebook update. Fused.
__global__ void __launch_bounds__(1024) k_ema(const float* __restrict__ ema_cs,
                                              const float* __restrict__ ema_w,
                                              const float* __restrict__ cs,
                                              const float* __restrict__ sumenc,
                                              float* __restrict__ newemb,
                                              float* __restrict__ out) {
    int k = threadIdx.x;  // 0..1023 == NE
    float c = cs[k];
    float ncs = 0.99f * ema_cs[k] + (1.0f - 0.99f) * c;
    float p = c * (1.0f / (float)NVEC);
    float e = p * logf(p + 1e-10f);
    float rn_ = ncs, re_ = e;
#pragma unroll
    for (int o = 32; o > 0; o >>= 1) {
        rn_ += __shfl_down(rn_, o, 64);
        re_ += __shfl_down(re_, o, 64);
    }
    __shared__ float sn[16], se_[16];
    __shared__ float s_n;
    int wave = k >> 6, lane = k & 63;
    if (lane == 0) { sn[wave] = rn_; se_[wave] = re_; }
    __syncthreads();
    if (k == 0) {
        float tn = 0.f, te = 0.f;
#pragma unroll
        for (int w = 0; w < 16; ++w) { tn += sn[w]; te += se_[w]; }
        s_n = tn;
        out[O_PERP] = expf(-te);
    }
    __syncthreads();
    float nt = s_n;
    float csn = (ncs + 1e-5f) / (nt + 1024.0f * 1e-5f) * nt;
    __shared__ float s_csn[NE];
    s_csn[k] = csn;
    __syncthreads();
    for (int t = k; t < NE * ED; t += 1024) {  // coalesced
        float nw = 0.99f * ema_w[t] + (1.0f - 0.99f) * sumenc[t];
        newemb[t] = nw / s_csn[t >> 6];
    }
}

// 2048 blocks x 256 threads x 4 elems. Per-block partial loss, one plain store.
__global__ void __launch_bounds__(256) k_zq(const float* __restrict__ z,
                                            const int* __restrict__ idx,
                                            const float* __restrict__ newemb,
                                            float* __restrict__ out,
                                            float* __restrict__ lossp) {
    float local = 0.f;
#pragma unroll
    for (int i = 0; i < 4; ++i) {
        int t = blockIdx.x * 256 + threadIdx.x + i * 524288;
        int b = t >> 16, c = (t >> 10) & 63, hw = t & 1023;
        int n = (b << 10) | hw;
        float e = newemb[idx[n] * ED + c];
        float zv = z[t];
        float diff = e - zv;             // z_q - z
        out[O_ZQ + t] = zv + diff;       // straight-through: z + (z_q - z)
        local = fmaf(diff, diff, local);
    }
#pragma unroll
    for (int o = 32; o > 0; o >>= 1) local += __shfl_down(local, o, 64);
    __shared__ float sp[4];
    int wave = threadIdx.x >> 6;
    if ((threadIdx.x & 63) == 0) sp[wave] = local;
    __syncthreads();
    if (threadIdx.x == 0)
        lossp[blockIdx.x] = (sp[0] + sp[1]) + (sp[2] + sp[3]);
}

// One block, 256 threads: reduce 2048 partials -> loss.
__global__ void __launch_bounds__(256) k_fin(const float* __restrict__ lossp,
                                             float* __restrict__ out) {
    float v = 0.f;
#pragma unroll
    for (int i = 0; i < 8; ++i) v += lossp[i * 256 + threadIdx.x];
#pragma unroll
    for (int o = 32; o > 0; o >>= 1) v += __shfl_down(v, o, 64);
    __shared__ float sp[4];
    int wave = threadIdx.x >> 6;
    if ((threadIdx.x & 63) == 0) sp[wave] = v;
    __syncthreads();
    if (threadIdx.x == 0)
        out[O_LOSS] = 0.25f * (((sp[0] + sp[1]) + (sp[2] + sp[3])) * (1.0f / (float)TOT));
}

extern "C" void kernel_launch(void* const* d_in, const int* in_sizes, int n_in,
                              void* d_out, int out_size, void* d_ws, size_t ws_size,
                              hipStream_t stream) {
    const float* z      = (const float*)d_in[0];
    const float* emb    = (const float*)d_in[1];
    const float* ema_cs = (const float*)d_in[2];
    const float* ema_w  = (const float*)d_in[3];
    float* out = (float*)d_out;
    float* ws  = (float*)d_ws;

    k_dist<<<512, 256, 0, stream>>>(z, emb, (int*)(ws + W_PIDX), out);
    k_sumenc<<<NE, 256, 0, stream>>>((const int*)(ws + W_PIDX), z, ws + W_CS,
                                     ws + W_SUMENC);
    k_ema<<<1, 1024, 0, stream>>>(ema_cs, ema_w, ws + W_CS, ws + W_SUMENC,
                                  ws + W_NEWEMB, out);
    k_zq<<<2048, 256, 0, stream>>>(z, (const int*)(ws + W_PIDX), ws + W_NEWEMB, out,
                                   ws + W_LOSSP);
    k_fin<<<1, 256, 0, stream>>>(ws + W_LOSSP, out);
}

// Round 13
// 292.560 us; speedup vs baseline: 1.0031x; 1.0031x over previous
//
#include <hip/hip_runtime.h>
#include <math.h>

#define NVEC 32768   // 32*32*32 vectors
#define NE   1024    // codebook entries
#define ED   64      // embedding dim
#define TOT  2097152 // NVEC*ED total z elements
#define NCHUNK 8     // code chunks inside k_dist
#define CHUNK  128   // codes per chunk
#define MT     64    // vectors per k_dist block

// d_out offsets (in floats): loss | z_q_st | perplexity | min_encodings | idx
#define O_LOSS   0
#define O_ZQ     1
#define O_PERP   2097153
#define O_MINENC 2097154
#define O_IDX    35651586

// d_ws offsets (in floats). No ws memset: every cell read has a producer.
#define W_PIDX   0        // [32768] final idx (int), written by k_dist
#define W_CS     32768    // [1024]
#define W_SUMENC 33792    // [1024*64]
#define W_NEWEMB 99328    // [1024*64]
#define W_LOSSP  164864   // [2048]

// R12 post-mortem: (1) B-staging scatter was an 8-way bank conflict
// (SQ_LDS_BANK_CONFLICT=7.3M): any 16B-aligned stride gives bank-step
// {0,16} for c-step-4. Fix: k-quad swizzle phys_q=(k4+c4)&31 — stores
// spread over all 32 banks (k4 wave-uniform per store, c4 spans 0..15),
// reads stay broadcast-grouped and conflict-free. (2) the fused one-hot
// tail wrote 134 MB as an all-blocks-at-once burst at 1.25 TB/s (~45 µs);
// split to k_onehot with a streaming-friendly grid. Numerics bit-identical
// to R12 (passed): same FMA chains, same pairwise zsq/esq, same (d,i)
// lexicographic merge == np.argmin first-index semantics.
__global__ void __launch_bounds__(256, 3) k_dist(const float* __restrict__ z,
                                                 const float* __restrict__ emb,
                                                 int* __restrict__ fidx,
                                                 float* __restrict__ out) {
    __shared__ __align__(16) float s_a[64 * 64];    // [c][m] : 2*z (16 KB)
    __shared__ __align__(16) float s_b[64 * 132];   // [c][k-swizzled] (33 KB)
    __shared__ float s_esq[CHUNK];
    __shared__ float s_zsq[MT];

    int tid = threadIdx.x;
    int n0 = blockIdx.x * MT;
    int b = n0 >> 10, hw0 = n0 & 1023;  // MT=64 tile never crosses a b boundary
    const float* zb = z + b * 65536 + hw0;

    // Stage A once: 64c x 64m = 1024 float4, coalesced; store 2*z (exact x2)
#pragma unroll
    for (int j = 0; j < 4; ++j) {
        int f4i = j * 256 + tid;
        int c = f4i >> 4, pos = (f4i & 15) * 4;
        float4 v = *(const float4*)(zb + (c << 10) + pos);
        v.x = __fmul_rn(2.0f, v.x);
        v.y = __fmul_rn(2.0f, v.y);
        v.z = __fmul_rn(2.0f, v.z);
        v.w = __fmul_rn(2.0f, v.w);
        *(float4*)(s_a + c * 64 + pos) = v;
    }
    __syncthreads();

    // zsq once (threads 0..63): np-pairwise over z; from (2z): exact x0.25.
    if (tid < MT) {
        float r[8];
#pragma unroll
        for (int j = 0; j < 8; ++j) {
            float v = s_a[j * 64 + tid];
            r[j] = __fmul_rn(v, v);
        }
#pragma unroll
        for (int i = 8; i < 64; i += 8)
#pragma unroll
            for (int j = 0; j < 8; ++j) {
                float v = s_a[(i + j) * 64 + tid];
                r[j] = __fadd_rn(r[j], __fmul_rn(v, v));
            }
        s_zsq[tid] = __fmul_rn(0.25f, __fadd_rn(
            __fadd_rn(__fadd_rn(r[0], r[1]), __fadd_rn(r[2], r[3])),
            __fadd_rn(__fadd_rn(r[4], r[5]), __fadd_rn(r[6], r[7]))));
    }
    __syncthreads();

    int mi = tid & 15, ki = tid >> 4;
    int mbase = mi * 4, kbase = ki * 8;
    float zs[4];
#pragma unroll
    for (int mu = 0; mu < 4; ++mu) zs[mu] = s_zsq[mbase + mu];

    float bd[4];
    int bix[4];
#pragma unroll
    for (int mu = 0; mu < 4; ++mu) { bd[mu] = 3.4e38f; bix[mu] = kbase; }

    for (int q = 0; q < NCHUNK; ++q) {
        int k0 = q * CHUNK;
        __syncthreads();  // previous chunk's readers of s_b/s_esq are done
        // Stage B transposed+swizzled: phys quad (k4+c4)&31. Per store
        // instruction k4 is wave-uniform, c4 spans 0..15 -> 32 banks, 2-way.
#pragma unroll
        for (int j = 0; j < 8; ++j) {
            int f4i = j * 256 + tid;
            int kl = f4i >> 4, c4 = f4i & 15;
            float4 v = *(const float4*)(emb + (size_t)(k0 + kl) * ED + c4 * 4);
            int base = ((( kl >> 2) + c4) & 31) * 4 + (kl & 3);
            s_b[(c4 * 4 + 0) * 132 + base] = v.x;
            s_b[(c4 * 4 + 1) * 132 + base] = v.y;
            s_b[(c4 * 4 + 2) * 132 + base] = v.z;
            s_b[(c4 * 4 + 3) * 132 + base] = v.w;
        }
        // esq for this chunk from GLOBAL (np-pairwise, threads 0..127)
        if (tid < CHUNK) {
            const float* ep = emb + (size_t)(k0 + tid) * ED;
            float r[8];
#pragma unroll
            for (int j = 0; j < 8; ++j) r[j] = __fmul_rn(ep[j], ep[j]);
#pragma unroll
            for (int i = 8; i < 64; i += 8)
#pragma unroll
                for (int j = 0; j < 8; ++j)
                    r[j] = __fadd_rn(r[j], __fmul_rn(ep[i + j], ep[i + j]));
            s_esq[tid] = __fadd_rn(
                __fadd_rn(__fadd_rn(r[0], r[1]), __fadd_rn(r[2], r[3])),
                __fadd_rn(__fadd_rn(r[4], r[5]), __fadd_rn(r[6], r[7])));
        }
        __syncthreads();

        float acc[4][8];
#pragma unroll
        for (int mu = 0; mu < 4; ++mu)
#pragma unroll
            for (int ku = 0; ku < 8; ++ku) acc[mu][ku] = 0.f;

#pragma unroll 4
        for (int c = 0; c < 64; ++c) {
            int c4 = c >> 2;
            float4 av = *(const float4*)(s_a + c * 64 + mbase);
            float4 b0 = *(const float4*)(s_b + c * 132 + ((2 * ki + c4) & 31) * 4);
            float4 b1 = *(const float4*)(s_b + c * 132 + ((2 * ki + 1 + c4) & 31) * 4);
#pragma unroll
            for (int mu = 0; mu < 4; ++mu) {
                float a = (&av.x)[mu];
                acc[mu][0] = __fmaf_rn(a, b0.x, acc[mu][0]);
                acc[mu][1] = __fmaf_rn(a, b0.y, acc[mu][1]);
                acc[mu][2] = __fmaf_rn(a, b0.z, acc[mu][2]);
                acc[mu][3] = __fmaf_rn(a, b0.w, acc[mu][3]);
                acc[mu][4] = __fmaf_rn(a, b1.x, acc[mu][4]);
                acc[mu][5] = __fmaf_rn(a, b1.y, acc[mu][5]);
                acc[mu][6] = __fmaf_rn(a, b1.z, acc[mu][6]);
                acc[mu][7] = __fmaf_rn(a, b1.w, acc[mu][7]);
            }
        }

        // d = fl(fl(zsq+esq) - dot2); running per-thread argmin (k ascending)
#pragma unroll
        for (int mu = 0; mu < 4; ++mu)
#pragma unroll
            for (int ku = 0; ku < 8; ++ku) {
                float d = __fsub_rn(__fadd_rn(zs[mu], s_esq[kbase + ku]),
                                    acc[mu][ku]);
                if (d < bd[mu]) { bd[mu] = d; bix[mu] = k0 + kbase + ku; }
            }
    }

    // Merge 16 ki candidates per m with lexicographic (d, i) min ==
    // np.argmin lowest-index-among-minima. Reuse s_b as scratch.
    __syncthreads();
    float* red_d = s_b;               // [16][64]
    int* red_i = (int*)(s_b + 1024);  // [16][64]
#pragma unroll
    for (int mu = 0; mu < 4; ++mu) {
        red_d[ki * 64 + mbase + mu] = bd[mu];
        red_i[ki * 64 + mbase + mu] = bix[mu];
    }
    __syncthreads();
    if (tid < MT) {
        float best = red_d[tid];
        int bi = red_i[tid];
#pragma unroll
        for (int q = 1; q < 16; ++q) {
            float d = red_d[q * 64 + tid];
            int i = red_i[q * 64 + tid];
            if (d < best || (d == best && i < bi)) { best = d; bi = i; }
        }
        fidx[n0 + tid] = bi;
        out[O_IDX + n0 + tid] = (float)bi;
    }
}

// One-hot writer: 2048 blocks x 16 rows, one row per pass. Row start is
// O_MINENC + r*1024 ≡ 2 mod 4 floats -> col 2 is 16B-aligned: thread t<254
// stores float4 at col 2+4t; t=254/255 store the head/tail float2.
__global__ void __launch_bounds__(256) k_onehot(const int* __restrict__ idx,
                                                float* __restrict__ out) {
    __shared__ int sbi[16];
    int r0 = blockIdx.x * 16;
    if (threadIdx.x < 16) sbi[threadIdx.x] = idx[r0 + threadIdx.x];
    __syncthreads();
    int t = threadIdx.x;
    for (int r = 0; r < 16; ++r) {
        int rbi = sbi[r];
        float* rp = out + O_MINENC + (size_t)(r0 + r) * NE;
        if (t < 254) {
            int col = 2 + t * 4;
            float4 v;
            v.x = (col == rbi) ? 1.0f : 0.0f;
            v.y = (col + 1 == rbi) ? 1.0f : 0.0f;
            v.z = (col + 2 == rbi) ? 1.0f : 0.0f;
            v.w = (col + 3 == rbi) ? 1.0f : 0.0f;
            *(float4*)(rp + col) = v;
        } else if (t == 254) {
            float2 v;
            v.x = (0 == rbi) ? 1.0f : 0.0f;
            v.y = (1 == rbi) ? 1.0f : 0.0f;
            *(float2*)(rp) = v;
        } else {
            float2 v;
            v.x = (1022 == rbi) ? 1.0f : 0.0f;
            v.y = (1023 == rbi) ? 1.0f : 0.0f;
            *(float2*)(rp + 1022) = v;
        }
    }
}

// Gather-based segment sum: one block per code k, 4 waves. Ballot-scan idx;
// members accumulated lane=element; popcount -> cs. Deterministic. No atomics.
__global__ void __launch_bounds__(256) k_sumenc(const int* __restrict__ idx,
                                                const float* __restrict__ z,
                                                float* __restrict__ cs,
                                                float* __restrict__ sumenc) {
    int k = blockIdx.x;
    int wave = threadIdx.x >> 6, lane = threadIdx.x & 63;
    float acc = 0.f;
    int cnt = 0;
    int base = wave * 8192;
    for (int it = 0; it < 128; ++it) {
        int n0 = base + it * 64;
        int idv = idx[n0 + lane];
        unsigned long long m = __ballot(idv == k);
        cnt += __popcll(m);
        while (m) {
            int bit = __ffsll((unsigned long long)m) - 1;  // ascending n
            m &= m - 1;
            int n = n0 + bit;
            int b = n >> 10, hw = n & 1023;
            acc = __fadd_rn(acc, z[b * 65536 + lane * 1024 + hw]);  // element c = lane
        }
    }
    __shared__ float sacc[4][64];
    __shared__ int scnt[4];
    sacc[wave][lane] = acc;
    if (lane == 0) scnt[wave] = cnt;
    __syncthreads();
    if (wave == 0) {
        float t = __fadd_rn(__fadd_rn(sacc[0][lane], sacc[1][lane]),
                            __fadd_rn(sacc[2][lane], sacc[3][lane]));
        sumenc[k * ED + lane] = t;
        if (lane == 0) cs[k] = (float)(scnt[0] + scnt[1] + scnt[2] + scnt[3]);
    }
}

// Single block, 1024 threads: EMA cluster-size + ntot/entropy reductions +
// perplexity + codebook update. Fused.
__global__ void __launch_bounds__(1024) k_ema(const float* __restrict__ ema_cs,
                                              const float* __restrict__ ema_w,
                                              const float* __restrict__ cs,
                                              const float* __restrict__ sumenc,
                                              float* __restrict__ newemb,
                                              float* __restrict__ out) {
    int k = threadIdx.x;  // 0..1023 == NE
    float c = cs[k];
    float ncs = 0.99f * ema_cs[k] + (1.0f - 0.99f) * c;
    float p = c * (1.0f / (float)NVEC);
    float e = p * logf(p + 1e-10f);
    float rn_ = ncs, re_ = e;
#pragma unroll
    for (int o = 32; o > 0; o >>= 1) {
        rn_ += __shfl_down(rn_, o, 64);
        re_ += __shfl_down(re_, o, 64);
    }
    __shared__ float sn[16], se_[16];
    __shared__ float s_n;
    int wave = k >> 6, lane = k & 63;
    if (lane == 0) { sn[wave] = rn_; se_[wave] = re_; }
    __syncthreads();
    if (k == 0) {
        float tn = 0.f, te = 0.f;
#pragma unroll
        for (int w = 0; w < 16; ++w) { tn += sn[w]; te += se_[w]; }
        s_n = tn;
        out[O_PERP] = expf(-te);
    }
    __syncthreads();
    float nt = s_n;
    float csn = (ncs + 1e-5f) / (nt + 1024.0f * 1e-5f) * nt;
    __shared__ float s_csn[NE];
    s_csn[k] = csn;
    __syncthreads();
    for (int t = k; t < NE * ED; t += 1024) {  // coalesced
        float nw = 0.99f * ema_w[t] + (1.0f - 0.99f) * sumenc[t];
        newemb[t] = nw / s_csn[t >> 6];
    }
}

// 2048 blocks x 256 threads x 4 elems. Per-block partial loss, one plain store.
__global__ void __launch_bounds__(256) k_zq(const float* __restrict__ z,
                                            const int* __restrict__ idx,
                                            const float* __restrict__ newemb,
                                            float* __restrict__ out,
                                            float* __restrict__ lossp) {
    float local = 0.f;
#pragma unroll
    for (int i = 0; i < 4; ++i) {
        int t = blockIdx.x * 256 + threadIdx.x + i * 524288;
        int b = t >> 16, c = (t >> 10) & 63, hw = t & 1023;
        int n = (b << 10) | hw;
        float e = newemb[idx[n] * ED + c];
        float zv = z[t];
        float diff = e - zv;             // z_q - z
        out[O_ZQ + t] = zv + diff;       // straight-through: z + (z_q - z)
        local = fmaf(diff, diff, local);
    }
#pragma unroll
    for (int o = 32; o > 0; o >>= 1) local += __shfl_down(local, o, 64);
    __shared__ float sp[4];
    int wave = threadIdx.x >> 6;
    if ((threadIdx.x & 63) == 0) sp[wave] = local;
    __syncthreads();
    if (threadIdx.x == 0)
        lossp[blockIdx.x] = (sp[0] + sp[1]) + (sp[2] + sp[3]);
}

// One block, 256 threads: reduce 2048 partials -> loss.
__global__ void __launch_bounds__(256) k_fin(const float* __restrict__ lossp,
                                             float* __restrict__ out) {
    float v = 0.f;
#pragma unroll
    for (int i = 0; i < 8; ++i) v += lossp[i * 256 + threadIdx.x];
#pragma unroll
    for (int o = 32; o > 0; o >>= 1) v += __shfl_down(v, o, 64);
    __shared__ float sp[4];
    int wave = threadIdx.x >> 6;
    if ((threadIdx.x & 63) == 0) sp[wave] = v;
    __syncthreads();
    if (threadIdx.x == 0)
        out[O_LOSS] = 0.25f * (((sp[0] + sp[1]) + (sp[2] + sp[3])) * (1.0f / (float)TOT));
}

extern "C" void kernel_launch(void* const* d_in, const int* in_sizes, int n_in,
                              void* d_out, int out_size, void* d_ws, size_t ws_size,
                              hipStream_t stream) {
    const float* z      = (const float*)d_in[0];
    const float* emb    = (const float*)d_in[1];
    const float* ema_cs = (const float*)d_in[2];
    const float* ema_w  = (const float*)d_in[3];
    float* out = (float*)d_out;
    float* ws  = (float*)d_ws;

    k_dist<<<512, 256, 0, stream>>>(z, emb, (int*)(ws + W_PIDX), out);
    k_onehot<<<2048, 256, 0, stream>>>((const int*)(ws + W_PIDX), out);
    k_sumenc<<<NE, 256, 0, stream>>>((const int*)(ws + W_PIDX), z, ws + W_CS,
                                     ws + W_SUMENC);
    k_ema<<<1, 1024, 0, stream>>>(ema_cs, ema_w, ws + W_CS, ws + W_SUMENC,
                                  ws + W_NEWEMB, out);
    k_zq<<<2048, 256, 0, stream>>>(z, (const int*)(ws + W_PIDX), ws + W_NEWEMB, out,
                                   ws + W_LOSSP);
    k_fin<<<1, 256, 0, stream>>>(ws + W_LOSSP, out);
}

// Round 14
// 285.777 us; speedup vs baseline: 1.0269x; 1.0237x over previous
//
#include <hip/hip_runtime.h>
#include <math.h>

#define NVEC 32768   // 32*32*32 vectors
#define NE   1024    // codebook entries
#define ED   64      // embedding dim
#define TOT  2097152 // NVEC*ED total z elements
#define NCHUNK 8     // code chunks inside k_dist
#define CHUNK  128   // codes per chunk
#define MT     64    // vectors per k_dist block

// d_out offsets (in floats): loss | z_q_st | perplexity | min_encodings | idx
#define O_LOSS   0
#define O_ZQ     1
#define O_PERP   2097153
#define O_MINENC 2097154
#define O_IDX    35651586

// d_ws offsets (in floats). No ws memset: every cell read has a producer.
#define W_PIDX   0        // [32768] final idx (int), written by k_dist
#define W_CS     32768    // [1024]
#define W_SUMENC 33792    // [1024*64]
#define W_NEWEMB 99328    // [1024*64]
#define W_LOSSP  164864   // [2048]

// R13 post-mortem: absmax regressed 0.001 -> 1.0 — k_onehot never wrote cols
// 1018..1021 (1024 = 2 + 254*4 + 6: the tail is 6 floats, not 2), so rows
// with code in {1018..1021} lost their 1.0. Fixed here and fused into k_zq
// (same 2048-block grid, 16 rows/block) — one fewer dispatch, stores overlap
// k_zq's streaming. k_dist unchanged from R13 (swizzled staging, conflict-free).
__global__ void __launch_bounds__(256, 3) k_dist(const float* __restrict__ z,
                                                 const float* __restrict__ emb,
                                                 int* __restrict__ fidx,
                                                 float* __restrict__ out) {
    __shared__ __align__(16) float s_a[64 * 64];    // [c][m] : 2*z (16 KB)
    __shared__ __align__(16) float s_b[64 * 132];   // [c][k-swizzled] (33 KB)
    __shared__ float s_esq[CHUNK];
    __shared__ float s_zsq[MT];

    int tid = threadIdx.x;
    int n0 = blockIdx.x * MT;
    int b = n0 >> 10, hw0 = n0 & 1023;  // MT=64 tile never crosses a b boundary
    const float* zb = z + b * 65536 + hw0;

    // Stage A once: 64c x 64m = 1024 float4, coalesced; store 2*z (exact x2)
#pragma unroll
    for (int j = 0; j < 4; ++j) {
        int f4i = j * 256 + tid;
        int c = f4i >> 4, pos = (f4i & 15) * 4;
        float4 v = *(const float4*)(zb + (c << 10) + pos);
        v.x = __fmul_rn(2.0f, v.x);
        v.y = __fmul_rn(2.0f, v.y);
        v.z = __fmul_rn(2.0f, v.z);
        v.w = __fmul_rn(2.0f, v.w);
        *(float4*)(s_a + c * 64 + pos) = v;
    }
    __syncthreads();

    // zsq once (threads 0..63): np-pairwise over z; from (2z): exact x0.25.
    if (tid < MT) {
        float r[8];
#pragma unroll
        for (int j = 0; j < 8; ++j) {
            float v = s_a[j * 64 + tid];
            r[j] = __fmul_rn(v, v);
        }
#pragma unroll
        for (int i = 8; i < 64; i += 8)
#pragma unroll
            for (int j = 0; j < 8; ++j) {
                float v = s_a[(i + j) * 64 + tid];
                r[j] = __fadd_rn(r[j], __fmul_rn(v, v));
            }
        s_zsq[tid] = __fmul_rn(0.25f, __fadd_rn(
            __fadd_rn(__fadd_rn(r[0], r[1]), __fadd_rn(r[2], r[3])),
            __fadd_rn(__fadd_rn(r[4], r[5]), __fadd_rn(r[6], r[7]))));
    }
    __syncthreads();

    int mi = tid & 15, ki = tid >> 4;
    int mbase = mi * 4, kbase = ki * 8;
    float zs[4];
#pragma unroll
    for (int mu = 0; mu < 4; ++mu) zs[mu] = s_zsq[mbase + mu];

    float bd[4];
    int bix[4];
#pragma unroll
    for (int mu = 0; mu < 4; ++mu) { bd[mu] = 3.4e38f; bix[mu] = kbase; }

    for (int q = 0; q < NCHUNK; ++q) {
        int k0 = q * CHUNK;
        __syncthreads();  // previous chunk's readers of s_b/s_esq are done
        // Stage B transposed+swizzled: phys quad (k4+c4)&31. Per store
        // instruction k4 is wave-uniform, c4 spans 0..15 -> 32 banks, 2-way.
#pragma unroll
        for (int j = 0; j < 8; ++j) {
            int f4i = j * 256 + tid;
            int kl = f4i >> 4, c4 = f4i & 15;
            float4 v = *(const float4*)(emb + (size_t)(k0 + kl) * ED + c4 * 4);
            int base = ((( kl >> 2) + c4) & 31) * 4 + (kl & 3);
            s_b[(c4 * 4 + 0) * 132 + base] = v.x;
            s_b[(c4 * 4 + 1) * 132 + base] = v.y;
            s_b[(c4 * 4 + 2) * 132 + base] = v.z;
            s_b[(c4 * 4 + 3) * 132 + base] = v.w;
        }
        // esq for this chunk from GLOBAL (np-pairwise, threads 0..127)
        if (tid < CHUNK) {
            const float* ep = emb + (size_t)(k0 + tid) * ED;
            float r[8];
#pragma unroll
            for (int j = 0; j < 8; ++j) r[j] = __fmul_rn(ep[j], ep[j]);
#pragma unroll
            for (int i = 8; i < 64; i += 8)
#pragma unroll
                for (int j = 0; j < 8; ++j)
                    r[j] = __fadd_rn(r[j], __fmul_rn(ep[i + j], ep[i + j]));
            s_esq[tid] = __fadd_rn(
                __fadd_rn(__fadd_rn(r[0], r[1]), __fadd_rn(r[2], r[3])),
                __fadd_rn(__fadd_rn(r[4], r[5]), __fadd_rn(r[6], r[7])));
        }
        __syncthreads();

        float acc[4][8];
#pragma unroll
        for (int mu = 0; mu < 4; ++mu)
#pragma unroll
            for (int ku = 0; ku < 8; ++ku) acc[mu][ku] = 0.f;

#pragma unroll 4
        for (int c = 0; c < 64; ++c) {
            int c4 = c >> 2;
            float4 av = *(const float4*)(s_a + c * 64 + mbase);
            float4 b0 = *(const float4*)(s_b + c * 132 + ((2 * ki + c4) & 31) * 4);
            float4 b1 = *(const float4*)(s_b + c * 132 + ((2 * ki + 1 + c4) & 31) * 4);
#pragma unroll
            for (int mu = 0; mu < 4; ++mu) {
                float a = (&av.x)[mu];
                acc[mu][0] = __fmaf_rn(a, b0.x, acc[mu][0]);
                acc[mu][1] = __fmaf_rn(a, b0.y, acc[mu][1]);
                acc[mu][2] = __fmaf_rn(a, b0.z, acc[mu][2]);
                acc[mu][3] = __fmaf_rn(a, b0.w, acc[mu][3]);
                acc[mu][4] = __fmaf_rn(a, b1.x, acc[mu][4]);
                acc[mu][5] = __fmaf_rn(a, b1.y, acc[mu][5]);
                acc[mu][6] = __fmaf_rn(a, b1.z, acc[mu][6]);
                acc[mu][7] = __fmaf_rn(a, b1.w, acc[mu][7]);
            }
        }

        // d = fl(fl(zsq+esq) - dot2); running per-thread argmin (k ascending)
#pragma unroll
        for (int mu = 0; mu < 4; ++mu)
#pragma unroll
            for (int ku = 0; ku < 8; ++ku) {
                float d = __fsub_rn(__fadd_rn(zs[mu], s_esq[kbase + ku]),
                                    acc[mu][ku]);
                if (d < bd[mu]) { bd[mu] = d; bix[mu] = k0 + kbase + ku; }
            }
    }

    // Merge 16 ki candidates per m with lexicographic (d, i) min ==
    // np.argmin lowest-index-among-minima. Reuse s_b as scratch.
    __syncthreads();
    float* red_d = s_b;               // [16][64]
    int* red_i = (int*)(s_b + 1024);  // [16][64]
#pragma unroll
    for (int mu = 0; mu < 4; ++mu) {
        red_d[ki * 64 + mbase + mu] = bd[mu];
        red_i[ki * 64 + mbase + mu] = bix[mu];
    }
    __syncthreads();
    if (tid < MT) {
        float best = red_d[tid];
        int bi = red_i[tid];
#pragma unroll
        for (int q = 1; q < 16; ++q) {
            float d = red_d[q * 64 + tid];
            int i = red_i[q * 64 + tid];
            if (d < best || (d == best && i < bi)) { best = d; bi = i; }
        }
        fidx[n0 + tid] = bi;
        out[O_IDX + n0 + tid] = (float)bi;
    }
}

// Gather-based segment sum: one block per code k, 4 waves. Ballot-scan idx;
// members accumulated lane=element; popcount -> cs. Deterministic. No atomics.
__global__ void __launch_bounds__(256) k_sumenc(const int* __restrict__ idx,
                                                const float* __restrict__ z,
                                                float* __restrict__ cs,
                                                float* __restrict__ sumenc) {
    int k = blockIdx.x;
    int wave = threadIdx.x >> 6, lane = threadIdx.x & 63;
    float acc = 0.f;
    int cnt = 0;
    int base = wave * 8192;
    for (int it = 0; it < 128; ++it) {
        int n0 = base + it * 64;
        int idv = idx[n0 + lane];
        unsigned long long m = __ballot(idv == k);
        cnt += __popcll(m);
        while (m) {
            int bit = __ffsll((unsigned long long)m) - 1;  // ascending n
            m &= m - 1;
            int n = n0 + bit;
            int b = n >> 10, hw = n & 1023;
            acc = __fadd_rn(acc, z[b * 65536 + lane * 1024 + hw]);  // element c = lane
        }
    }
    __shared__ float sacc[4][64];
    __shared__ int scnt[4];
    sacc[wave][lane] = acc;
    if (lane == 0) scnt[wave] = cnt;
    __syncthreads();
    if (wave == 0) {
        float t = __fadd_rn(__fadd_rn(sacc[0][lane], sacc[1][lane]),
                            __fadd_rn(sacc[2][lane], sacc[3][lane]));
        sumenc[k * ED + lane] = t;
        if (lane == 0) cs[k] = (float)(scnt[0] + scnt[1] + scnt[2] + scnt[3]);
    }
}

// Single block, 1024 threads: EMA cluster-size + ntot/entropy reductions +
// perplexity + codebook update. Fused.
__global__ void __launch_bounds__(1024) k_ema(const float* __restrict__ ema_cs,
                                              const float* __restrict__ ema_w,
                                              const float* __restrict__ cs,
                                              const float* __restrict__ sumenc,
                                              float* __restrict__ newemb,
                                              float* __restrict__ out) {
    int k = threadIdx.x;  // 0..1023 == NE
    float c = cs[k];
    float ncs = 0.99f * ema_cs[k] + (1.0f - 0.99f) * c;
    float p = c * (1.0f / (float)NVEC);
    float e = p * logf(p + 1e-10f);
    float rn_ = ncs, re_ = e;
#pragma unroll
    for (int o = 32; o > 0; o >>= 1) {
        rn_ += __shfl_down(rn_, o, 64);
        re_ += __shfl_down(re_, o, 64);
    }
    __shared__ float sn[16], se_[16];
    __shared__ float s_n;
    int wave = k >> 6, lane = k & 63;
    if (lane == 0) { sn[wave] = rn_; se_[wave] = re_; }
    __syncthreads();
    if (k == 0) {
        float tn = 0.f, te = 0.f;
#pragma unroll
        for (int w = 0; w < 16; ++w) { tn += sn[w]; te += se_[w]; }
        s_n = tn;
        out[O_PERP] = expf(-te);
    }
    __syncthreads();
    float nt = s_n;
    float csn = (ncs + 1e-5f) / (nt + 1024.0f * 1e-5f) * nt;
    __shared__ float s_csn[NE];
    s_csn[k] = csn;
    __syncthreads();
    for (int t = k; t < NE * ED; t += 1024) {  // coalesced
        float nw = 0.99f * ema_w[t] + (1.0f - 0.99f) * sumenc[t];
        newemb[t] = nw / s_csn[t >> 6];
    }
}

// 2048 blocks x 256 threads: z_q + straight-through + loss partials + the
// one-hot rows (16 per block). One-hot coverage FIXED: row base is = 2 mod 4
// floats, so float4 at cols 2+4t (t<254) covers 2..1017; t=254 does the 2-col
// head; t=255 does float4 at 1018 (aligned) + float2 at 1022 -> full 0..1023.
__global__ void __launch_bounds__(256) k_zq(const float* __restrict__ z,
                                            const int* __restrict__ idx,
                                            const float* __restrict__ newemb,
                                            float* __restrict__ out,
                                            float* __restrict__ lossp) {
    __shared__ int sbi[16];
    if (threadIdx.x < 16) sbi[threadIdx.x] = idx[blockIdx.x * 16 + threadIdx.x];
    __syncthreads();

    float local = 0.f;
#pragma unroll
    for (int i = 0; i < 4; ++i) {
        int t = blockIdx.x * 256 + threadIdx.x + i * 524288;
        int b = t >> 16, c = (t >> 10) & 63, hw = t & 1023;
        int n = (b << 10) | hw;
        float e = newemb[idx[n] * ED + c];
        float zv = z[t];
        float diff = e - zv;             // z_q - z
        out[O_ZQ + t] = zv + diff;       // straight-through: z + (z_q - z)
        local = fmaf(diff, diff, local);
    }

    // one-hot rows r0..r0+15
    int t = threadIdx.x;
    int r0 = blockIdx.x * 16;
    for (int r = 0; r < 16; ++r) {
        int rbi = sbi[r];
        float* rp = out + O_MINENC + (size_t)(r0 + r) * NE;
        if (t < 254) {
            int col = 2 + t * 4;
            float4 v;
            v.x = (col == rbi) ? 1.0f : 0.0f;
            v.y = (col + 1 == rbi) ? 1.0f : 0.0f;
            v.z = (col + 2 == rbi) ? 1.0f : 0.0f;
            v.w = (col + 3 == rbi) ? 1.0f : 0.0f;
            *(float4*)(rp + col) = v;
        } else if (t == 254) {
            float2 v;
            v.x = (0 == rbi) ? 1.0f : 0.0f;
            v.y = (1 == rbi) ? 1.0f : 0.0f;
            *(float2*)(rp) = v;
        } else {
            float4 v;
            v.x = (1018 == rbi) ? 1.0f : 0.0f;
            v.y = (1019 == rbi) ? 1.0f : 0.0f;
            v.z = (1020 == rbi) ? 1.0f : 0.0f;
            v.w = (1021 == rbi) ? 1.0f : 0.0f;
            *(float4*)(rp + 1018) = v;
            float2 w;
            w.x = (1022 == rbi) ? 1.0f : 0.0f;
            w.y = (1023 == rbi) ? 1.0f : 0.0f;
            *(float2*)(rp + 1022) = w;
        }
    }

#pragma unroll
    for (int o = 32; o > 0; o >>= 1) local += __shfl_down(local, o, 64);
    __shared__ float sp[4];
    int wave = threadIdx.x >> 6;
    if ((threadIdx.x & 63) == 0) sp[wave] = local;
    __syncthreads();
    if (threadIdx.x == 0)
        lossp[blockIdx.x] = (sp[0] + sp[1]) + (sp[2] + sp[3]);
}

// One block, 256 threads: reduce 2048 partials -> loss.
__global__ void __launch_bounds__(256) k_fin(const float* __restrict__ lossp,
                                             float* __restrict__ out) {
    float v = 0.f;
#pragma unroll
    for (int i = 0; i < 8; ++i) v += lossp[i * 256 + threadIdx.x];
#pragma unroll
    for (int o = 32; o > 0; o >>= 1) v += __shfl_down(v, o, 64);
    __shared__ float sp[4];
    int wave = threadIdx.x >> 6;
    if ((threadIdx.x & 63) == 0) sp[wave] = v;
    __syncthreads();
    if (threadIdx.x == 0)
        out[O_LOSS] = 0.25f * (((sp[0] + sp[1]) + (sp[2] + sp[3])) * (1.0f / (float)TOT));
}

extern "C" void kernel_launch(void* const* d_in, const int* in_sizes, int n_in,
                              void* d_out, int out_size, void* d_ws, size_t ws_size,
                              hipStream_t stream) {
    const float* z      = (const float*)d_in[0];
    const float* emb    = (const float*)d_in[1];
    const float* ema_cs = (const float*)d_in[2];
    const float* ema_w  = (const float*)d_in[3];
    float* out = (float*)d_out;
    float* ws  = (float*)d_ws;

    k_dist<<<512, 256, 0, stream>>>(z, emb, (int*)(ws + W_PIDX), out);
    k_sumenc<<<NE, 256, 0, stream>>>((const int*)(ws + W_PIDX), z, ws + W_CS,
                                     ws + W_SUMENC);
    k_ema<<<1, 1024, 0, stream>>>(ema_cs, ema_w, ws + W_CS, ws + W_SUMENC,
                                  ws + W_NEWEMB, out);
    k_zq<<<2048, 256, 0, stream>>>(z, (const int*)(ws + W_PIDX), ws + W_NEWEMB, out,
                                   ws + W_LOSSP);
    k_fin<<<1, 256, 0, stream>>>(ws + W_LOSSP, out);
}